// Round 4
// baseline (221.412 us; speedup 1.0000x reference)
//
#include <hip/hip_runtime.h>
#include <hip/hip_bf16.h>
#include <math.h>

// Problem constants (all fp32 on the wire)
#define B_   4
#define T_   2048
#define DM   1024      // d_model
#define DH   256       // d_hidden
#define M_   (B_*T_)   // 8192 rows

typedef __bf16 bf16;
typedef __attribute__((ext_vector_type(8))) __bf16 bf16x8;
typedef __attribute__((ext_vector_type(4))) float  f32x4;

__device__ inline float sigmoidf_(float x) { return 1.0f / (1.0f + __expf(-x)); }

// T2-style LDS XOR swizzle: rows are 64 bf16 = 8 chunks of 16B.
// chunk' = chunk ^ (row & 7). Involution; same formula on write & read.
__device__ inline int swz8(int r, int c) { return (((c >> 3) ^ (r & 7)) << 3); }

// global -> LDS direct DMA, 16 B per lane (dest = wave-uniform base + lane*16;
// swizzled content via pre-swizzled per-lane global source, rule #21).
__device__ inline void gload16(const void* g, void* l) {
    __builtin_amdgcn_global_load_lds(
        (const __attribute__((address_space(1))) void*)g,
        (__attribute__((address_space(3))) void*)l, 16, 0, 0);
}

// ---- fused: transpose+convert 4 weights, and zero numb/denb ----------------
__global__ void transpose_cvt_all(const float* __restrict__ Wq, const float* __restrict__ Wk,
                                  const float* __restrict__ Wv, const float* __restrict__ Wo,
                                  bf16* __restrict__ Wq_t, bf16* __restrict__ Wk_t,
                                  bf16* __restrict__ Wv_t, bf16* __restrict__ Wo_t,
                                  float* __restrict__ nd)
{
    const int bid = blockIdx.x;
    if (bid >= 1024) {                      // zero numb+denb (contiguous 2048 f32)
        nd[(bid - 1024) * 256 + threadIdx.x] = 0.f;
        return;
    }
    __shared__ float tile[32][33];
    const int w = bid >> 8, t = bid & 255;
    const float* in; bf16* out; int R, C, sh;
    if      (w == 0) { in = Wq; out = Wq_t; R = DM; C = DH; sh = 3; }
    else if (w == 1) { in = Wk; out = Wk_t; R = DM; C = DH; sh = 3; }
    else if (w == 2) { in = Wv; out = Wv_t; R = DM; C = DH; sh = 3; }
    else             { in = Wo; out = Wo_t; R = DH; C = DM; sh = 5; }
    const int r0 = (t >> sh) * 32, c0 = (t & ((1 << sh) - 1)) * 32;
    const int tx = threadIdx.x & 31, ty = threadIdx.x >> 5;
    #pragma unroll
    for (int i = ty; i < 32; i += 8)
        tile[i][tx] = in[(long)(r0 + i) * C + c0 + tx];
    __syncthreads();
    #pragma unroll
    for (int i = ty; i < 32; i += 8)
        out[(long)(c0 + i) * R + r0 + tx] = (bf16)tile[tx][i];
}

// ---- projections: C_z = A_z @ W_z -> bf16 [M_][DH] in ws -------------------
// m93 geometry: tile 128x128, BK=64, 256 thr (4 waves, 2x2), 64x64 per wave
// (acc[4][4]) -> 16 MFMA per 8 ds_read_b128 (2x the old ratio, 4x the ILP).
// B DMA'd (pre-swizzled source), A reg-staged fp32->bf16, dbuf, 1 barrier/slab.
// Epilogue bounces C through LDS for bf16x8 coalesced stores.
__global__ __launch_bounds__(256, 2)
void gemm_proj(const float* __restrict__ qin, const float* __restrict__ kin,
               const float* __restrict__ vin,
               const bf16* __restrict__ Wq_t, const bf16* __restrict__ Wk_t,
               const bf16* __restrict__ Wv_t,
               bf16* __restrict__ Yb, bf16* __restrict__ Kb, bf16* __restrict__ Vb)
{
    __shared__ __align__(16) char smem[65536];
    auto As = reinterpret_cast<bf16 (*)[128][64]>(smem);           // 2 x 16 KB
    auto Bs = reinterpret_cast<bf16 (*)[128][64]>(smem + 32768);   // 2 x 16 KB

    const int z = blockIdx.z;
    const float* A  = (z == 0) ? qin  : (z == 1) ? kin  : vin;
    const bf16*  Wt = (z == 0) ? Wq_t : (z == 1) ? Wk_t : Wv_t;
    bf16*        C  = (z == 0) ? Yb   : (z == 1) ? Kb   : Vb;

    // XCD-aware tile swizzle (128 % 8 == 0).
    const int bid  = blockIdx.x;                  // 0..127
    const int tile = (bid & 7) * 16 + (bid >> 3);
    const int m0 = (tile >> 1) * 128;
    const int n0 = (tile & 1) * 128;

    const int tid = threadIdx.x, lane = tid & 63, wave = tid >> 6;
    const int wr = wave >> 1, wc = wave & 1;      // wave: 64m x 64n
    const int q4 = lane >> 4, l16 = lane & 15;

    f32x4 acc[4][4] = {};

    // A staging: thread -> (row 0..127, 32-col half). 32 floats/thread/slab.
    const int arow = tid >> 1, acb = (tid & 1) * 32;
    const float* aBase = &A[(long)(m0 + arow) * DM + acb];

    // B DMA: wave covers rows [wave*32, wave*32+32), 4 issues x 8 rows.
    const bf16* bS[4];
    #pragma unroll
    for (int i = 0; i < 4; ++i) {
        const int brow = wave * 32 + i * 8 + (lane >> 3);
        bS[i] = &Wt[(long)(n0 + brow) * DM + (((lane & 7) ^ (brow & 7)) * 8)];
    }

    f32x4 rA[8], rB[8];    // named register slots (all indices static)

    #define LOAD_A(slot, s) { _Pragma("unroll") for (int c = 0; c < 8; ++c) \
        slot[c] = *(const f32x4*)(aBase + (s) * 64 + c * 4); }
    #define STAGE_A(slot, buf) { _Pragma("unroll") for (int c = 0; c < 4; ++c) { \
        bf16x8 o_; _Pragma("unroll") for (int e = 0; e < 4; ++e) { \
            o_[e] = (bf16)slot[2*c][e]; o_[4+e] = (bf16)slot[2*c+1][e]; } \
        *(bf16x8*)&As[buf][arow][swz8(arow, acb + c * 8)] = o_; } }
    #define DMA_B(buf, s) { _Pragma("unroll") for (int i = 0; i < 4; ++i) \
        gload16(bS[i] + (s) * 64, &Bs[buf][wave * 32 + i * 8][0]); }
    #define MFMA_SLAB(buf) { _Pragma("unroll") for (int kk = 0; kk < 64; kk += 32) { \
        bf16x8 af[4], bfr[4]; \
        _Pragma("unroll") for (int mi = 0; mi < 4; ++mi) { \
            const int ra = wr * 64 + mi * 16 + l16; \
            af[mi] = *(const bf16x8*)&As[buf][ra][swz8(ra, kk + q4 * 8)]; } \
        _Pragma("unroll") for (int ni = 0; ni < 4; ++ni) { \
            const int rb = wc * 64 + ni * 16 + l16; \
            bfr[ni] = *(const bf16x8*)&Bs[buf][rb][swz8(rb, kk + q4 * 8)]; } \
        _Pragma("unroll") for (int mi = 0; mi < 4; ++mi) \
            _Pragma("unroll") for (int ni = 0; ni < 4; ++ni) \
                acc[mi][ni] = __builtin_amdgcn_mfma_f32_16x16x32_bf16(af[mi], bfr[ni], acc[mi][ni], 0, 0, 0); } }

    LOAD_A(rA, 0);
    DMA_B(0, 0);
    STAGE_A(rA, 0);
    LOAD_A(rB, 1);
    __syncthreads();

    for (int p = 0; p < 8; ++p) {               // 8 pairs = 16 slabs of BK=64
        const int e = 2 * p;
        // even slab e: compute buf0; stage slab e+1 -> buf1
        DMA_B(1, e + 1);
        STAGE_A(rB, 1);
        if (e + 2 < 16) LOAD_A(rA, e + 2);
        MFMA_SLAB(0);
        __syncthreads();
        // odd slab e+1: compute buf1; stage slab e+2 -> buf0
        if (e + 2 < 16) { DMA_B(0, e + 2); STAGE_A(rA, 0); }
        if (e + 3 < 16) LOAD_A(rB, e + 3);
        MFMA_SLAB(1);
        if (p < 7) __syncthreads();
    }
    #undef LOAD_A
    #undef STAGE_A
    #undef DMA_B

    // Epilogue: acc -> LDS (bf16, stride 136) -> bf16x8 coalesced stores.
    __syncthreads();
    auto Cb = reinterpret_cast<bf16 (*)[136]>(smem);
    #pragma unroll
    for (int mi = 0; mi < 4; ++mi)
        #pragma unroll
        for (int ni = 0; ni < 4; ++ni)
            #pragma unroll
            for (int r = 0; r < 4; ++r) {
                float v = acc[mi][ni][r];
                if (z == 0) v = sigmoidf_(v);
                Cb[wr * 64 + mi * 16 + q4 * 4 + r][wc * 64 + ni * 16 + l16] = (bf16)v;
            }
    __syncthreads();
    {
        const int row = tid >> 1, cb = (tid & 1) * 64;
        bf16* dst = &C[(long)(m0 + row) * DH + n0 + cb];
        #pragma unroll
        for (int c = 0; c < 8; ++c)
            *(bf16x8*)&dst[c * 8] = *(const bf16x8*)&Cb[row][cb + c * 8];
    }
}

// ---- exp-weighted reduction over j ----------------------------------------
// 64 blocks x 256 thr; 32 j per block (4 rounds of 8) -> 4x fewer atomics.
__global__ void reduce_kv(const bf16* __restrict__ Kb, const bf16* __restrict__ Vb,
                          float* __restrict__ numb, float* __restrict__ denb)
{
    __shared__ float red[2][4][B_][DH];     // [arr][wave][b][d] = 32 KB
    const int tid = threadIdx.x;
    const int g = tid & 31, jj = tid >> 5;  // 32 d-groups x 8 j
    const int d8 = g * 8;

    float sn[B_][8] = {}, sd[B_][8] = {};
    for (int t4 = 0; t4 < 4; ++t4) {
        const int j = blockIdx.x * 32 + t4 * 8 + jj;
        bf16x8 kx[B_], vx[B_];
        #pragma unroll
        for (int b = 0; b < B_; ++b) {
            kx[b] = *(const bf16x8*)&Kb[((long)b * T_ + j) * DH + d8];
            vx[b] = *(const bf16x8*)&Vb[((long)b * T_ + j) * DH + d8];
        }
        #pragma unroll
        for (int e = 0; e < 8; ++e) {
            float k0 = (float)kx[0][e], k1 = (float)kx[1][e];
            float k2 = (float)kx[2][e], k3 = (float)kx[3][e];
            float mx = fmaxf(fmaxf(k0, k1), fmaxf(k2, k3));
            float e0 = __expf(k0 - mx), e1 = __expf(k1 - mx);
            float e2 = __expf(k2 - mx), e3 = __expf(k3 - mx);
            sn[0][e] += e0 * (float)vx[0][e]; sd[0][e] += e0;
            sn[1][e] += e1 * (float)vx[1][e]; sd[1][e] += e1;
            sn[2][e] += e2 * (float)vx[2][e]; sd[2][e] += e2;
            sn[3][e] += e3 * (float)vx[3][e]; sd[3][e] += e3;
        }
    }
    #pragma unroll
    for (int b = 0; b < B_; ++b)
        #pragma unroll
        for (int e = 0; e < 8; ++e) {
            sn[b][e] += __shfl_xor(sn[b][e], 32);
            sd[b][e] += __shfl_xor(sd[b][e], 32);
        }
    const int w = tid >> 6;
    if ((tid & 32) == 0) {                  // jj even holds the pair sum
        #pragma unroll
        for (int b = 0; b < B_; ++b)
            #pragma unroll
            for (int e = 0; e < 8; ++e) {
                red[0][w][b][d8 + e] = sn[b][e];
                red[1][w][b][d8 + e] = sd[b][e];
            }
    }
    __syncthreads();
    #pragma unroll
    for (int o = tid; o < 2 * B_ * DH; o += 256) {
        const int arr = o >> 10, b = (o >> 8) & 3, d = o & 255;
        float s = red[arr][0][b][d] + red[arr][1][b][d]
                + red[arr][2][b][d] + red[arr][3][b][d];
        float* dst = (o < 1024) ? &numb[o] : &denb[o - 1024];
        atomicAdd(dst, s);
    }
}

// ---- output GEMM: out = (Yb * rv[b]) @ Wo, fp32 out ------------------------
// rv folded into A-staging (scale_wo kernel eliminated). Tile 128x128,
// 4 waves, K=256 (4 slabs), B = Wo_t DMA'd. fp32 epilogue via half-tile
// LDS bounce -> f32x4 stores.
__global__ __launch_bounds__(256, 2)
void gemm_out(const bf16* __restrict__ Yb, const bf16* __restrict__ Wo_t,
              const float* __restrict__ numb, const float* __restrict__ denb,
              float* __restrict__ out)
{
    __shared__ __align__(16) char smem[65536];
    auto As = reinterpret_cast<bf16 (*)[128][64]>(smem);           // 2 x 16 KB
    auto Bs = reinterpret_cast<bf16 (*)[128][64]>(smem + 32768);   // 2 x 16 KB
    __shared__ float rv_s[DH];

    // XCD-aware tile swizzle (512 % 8 == 0); n varies fastest within a chunk
    // so the 8 n-blocks sharing a Yb m-panel stay on one XCD's L2.
    const int bid  = blockIdx.x;                   // 0..511
    const int tile = (bid & 7) * 64 + (bid >> 3);
    const int m0 = (tile >> 3) * 128;
    const int n0 = (tile & 7) * 128;
    const int b  = m0 >> 11;                       // batch = m0/2048

    const int tid = threadIdx.x, lane = tid & 63, wave = tid >> 6;
    const int wr = wave >> 1, wc = wave & 1;
    const int q4 = lane >> 4, l16 = lane & 15;

    rv_s[tid] = numb[b * DH + tid] / denb[b * DH + tid];

    f32x4 acc[4][4] = {};

    const int arow = tid >> 1, acb = (tid & 1) * 32;
    const bf16* aBase = &Yb[(long)(m0 + arow) * DH + acb];

    const bf16* bS[4];
    #pragma unroll
    for (int i = 0; i < 4; ++i) {
        const int brow = wave * 32 + i * 8 + (lane >> 3);
        bS[i] = &Wo_t[(long)(n0 + brow) * DH + (((lane & 7) ^ (brow & 7)) * 8)];
    }

    bf16x8 rQA[4], rQB[4];
    #define LOAD_Q(slot, s) { _Pragma("unroll") for (int c = 0; c < 4; ++c) \
        slot[c] = *(const bf16x8*)(aBase + (s) * 64 + c * 8); }
    #define STAGE_Q(slot, buf, s) { _Pragma("unroll") for (int c = 0; c < 4; ++c) { \
        bf16x8 o_; _Pragma("unroll") for (int e = 0; e < 8; ++e) \
            o_[e] = (bf16)((float)slot[c][e] * rv_s[(s) * 64 + acb + c * 8 + e]); \
        *(bf16x8*)&As[buf][arow][swz8(arow, acb + c * 8)] = o_; } }
    #define DMA_B(buf, s) { _Pragma("unroll") for (int i = 0; i < 4; ++i) \
        gload16(bS[i] + (s) * 64, &Bs[buf][wave * 32 + i * 8][0]); }
    #define MFMA_SLAB(buf) { _Pragma("unroll") for (int kk = 0; kk < 64; kk += 32) { \
        bf16x8 af[4], bfr[4]; \
        _Pragma("unroll") for (int mi = 0; mi < 4; ++mi) { \
            const int ra = wr * 64 + mi * 16 + l16; \
            af[mi] = *(const bf16x8*)&As[buf][ra][swz8(ra, kk + q4 * 8)]; } \
        _Pragma("unroll") for (int ni = 0; ni < 4; ++ni) { \
            const int rb = wc * 64 + ni * 16 + l16; \
            bfr[ni] = *(const bf16x8*)&Bs[buf][rb][swz8(rb, kk + q4 * 8)]; } \
        _Pragma("unroll") for (int mi = 0; mi < 4; ++mi) \
            _Pragma("unroll") for (int ni = 0; ni < 4; ++ni) \
                acc[mi][ni] = __builtin_amdgcn_mfma_f32_16x16x32_bf16(af[mi], bfr[ni], acc[mi][ni], 0, 0, 0); } }

    LOAD_Q(rQA, 0);
    LOAD_Q(rQB, 1);
    DMA_B(0, 0);
    __syncthreads();              // rv_s ready (and Bs[0] DMA drained)
    STAGE_Q(rQA, 0, 0);
    DMA_B(1, 1);
    LOAD_Q(rQA, 2);
    __syncthreads();              // As[0] visible
    STAGE_Q(rQB, 1, 1);           // slab1 -> buf1
    LOAD_Q(rQB, 3);
    MFMA_SLAB(0);                 // slab0
    __syncthreads();
    DMA_B(0, 2);
    STAGE_Q(rQA, 0, 2);           // slab2 -> buf0
    MFMA_SLAB(1);                 // slab1
    __syncthreads();
    DMA_B(1, 3);
    STAGE_Q(rQB, 1, 3);           // slab3 -> buf1
    MFMA_SLAB(0);                 // slab2
    __syncthreads();
    MFMA_SLAB(1);                 // slab3
    #undef LOAD_Q
    #undef STAGE_Q
    #undef DMA_B

    // Epilogue: half-tile bounce (64 rows x 128 cols fp32, stride 132).
    auto Cbf = reinterpret_cast<float (*)[132]>(smem);
    #pragma unroll
    for (int h = 0; h < 2; ++h) {
        __syncthreads();          // tiles free / previous half stored
        if (wr == h) {
            #pragma unroll
            for (int mi = 0; mi < 4; ++mi)
                #pragma unroll
                for (int ni = 0; ni < 4; ++ni)
                    #pragma unroll
                    for (int r = 0; r < 4; ++r)
                        Cbf[mi * 16 + q4 * 4 + r][wc * 64 + ni * 16 + l16] = acc[mi][ni][r];
        }
        __syncthreads();
        const int row = tid >> 2, cb = (tid & 3) * 32;
        float* dst = &out[(long)(m0 + h * 64 + row) * DM + n0 + cb];
        #pragma unroll
        for (int c = 0; c < 8; ++c)
            *(f32x4*)&dst[c * 4] = *(const f32x4*)&Cbf[row][cb + c * 4];
    }
}

// ---------------- launch ----------------
extern "C" void kernel_launch(void* const* d_in, const int* in_sizes, int n_in,
                              void* d_out, int out_size, void* d_ws, size_t ws_size,
                              hipStream_t stream)
{
    const float* q  = (const float*)d_in[0];
    const float* k  = (const float*)d_in[1];
    const float* v  = (const float*)d_in[2];
    const float* Wq = (const float*)d_in[3];
    const float* Wk = (const float*)d_in[4];
    const float* Wv = (const float*)d_in[5];
    const float* Wo = (const float*)d_in[6];
    // d_in[7] = W_bias: provably unused (exp_pos_bias == ones)
    float* out = (float*)d_out;

    // Workspace: 14.02 MB
    char* ws = (char*)d_ws;
    bf16* Yb    = (bf16*)ws;  ws += (size_t)M_ * DH * sizeof(bf16);   // sigmoid(Q), 4 MB
    bf16* Kb    = (bf16*)ws;  ws += (size_t)M_ * DH * sizeof(bf16);   // 4 MB
    bf16* Vb    = (bf16*)ws;  ws += (size_t)M_ * DH * sizeof(bf16);   // 4 MB
    bf16* Wq_t  = (bf16*)ws;  ws += (size_t)DM * DH * sizeof(bf16);   // 0.5 MB
    bf16* Wk_t  = (bf16*)ws;  ws += (size_t)DM * DH * sizeof(bf16);
    bf16* Wv_t  = (bf16*)ws;  ws += (size_t)DM * DH * sizeof(bf16);
    bf16* Wo_t  = (bf16*)ws;  ws += (size_t)DM * DH * sizeof(bf16);
    float* numb = (float*)ws; ws += (size_t)B_ * DH * sizeof(float);  // 4 KB
    float* denb = (float*)ws; ws += (size_t)B_ * DH * sizeof(float);  // contiguous after numb

    transpose_cvt_all<<<1032, 256, 0, stream>>>(Wq, Wk, Wv, Wo,
                                                Wq_t, Wk_t, Wv_t, Wo_t, numb);

    gemm_proj<<<dim3(128, 1, 3), 256, 0, stream>>>(q, k, v, Wq_t, Wk_t, Wv_t,
                                                   Yb, Kb, Vb);
    reduce_kv<<<64, 256, 0, stream>>>(Kb, Vb, numb, denb);
    gemm_out<<<512, 256, 0, stream>>>(Yb, Wo_t, numb, denb, out);
}

// Round 7
// 199.449 us; speedup vs baseline: 1.1101x; 1.1101x over previous
//
#include <hip/hip_runtime.h>
#include <hip/hip_bf16.h>
#include <math.h>

// Problem constants (all fp32 on the wire)
#define B_   4
#define T_   2048
#define DM   1024      // d_model
#define DH   256       // d_hidden
#define M_   (B_*T_)   // 8192 rows

typedef __bf16 bf16;
typedef __attribute__((ext_vector_type(8))) __bf16 bf16x8;
typedef __attribute__((ext_vector_type(4))) float  f32x4;

__device__ inline float sigmoidf_(float x) { return 1.0f / (1.0f + __expf(-x)); }

// T2-style LDS XOR swizzle: rows are 64 bf16 = 8 chunks of 16B.
// chunk' = chunk ^ (row & 7). Involution; same formula on write & read.
__device__ inline int swz8(int r, int c) { return (((c >> 3) ^ (r & 7)) << 3); }

// ---- transpose+convert 4 weights (numb/denb zeroing no longer needed) ------
__global__ void transpose_cvt_all(const float* __restrict__ Wq, const float* __restrict__ Wk,
                                  const float* __restrict__ Wv, const float* __restrict__ Wo,
                                  bf16* __restrict__ Wq_t, bf16* __restrict__ Wk_t,
                                  bf16* __restrict__ Wv_t, bf16* __restrict__ Wo_t)
{
    const int bid = blockIdx.x;
    __shared__ float tile[32][33];
    const int w = bid >> 8, t = bid & 255;
    const float* in; bf16* out; int R, C, sh;
    if      (w == 0) { in = Wq; out = Wq_t; R = DM; C = DH; sh = 3; }
    else if (w == 1) { in = Wk; out = Wk_t; R = DM; C = DH; sh = 3; }
    else if (w == 2) { in = Wv; out = Wv_t; R = DM; C = DH; sh = 3; }
    else             { in = Wo; out = Wo_t; R = DH; C = DM; sh = 5; }
    const int r0 = (t >> sh) * 32, c0 = (t & ((1 << sh) - 1)) * 32;
    const int tx = threadIdx.x & 31, ty = threadIdx.x >> 5;
    #pragma unroll
    for (int i = ty; i < 32; i += 8)
        tile[i][tx] = in[(long)(r0 + i) * C + c0 + tx];
    __syncthreads();
    #pragma unroll
    for (int i = ty; i < 32; i += 8)
        out[(long)(c0 + i) * R + r0 + tx] = (bf16)tile[tx][i];
}

// ---- projections: C_z = A_z @ W_z -> bf16 [M_][DH] in ws -------------------
// ROUND-1 VERIFIED VERSION (passed, 48 us): tile 64x128, BK=64, 512 thr
// (8 waves = 2m x 4n), LDS double-buffer (1 barrier/slab) + ring-2 register
// prefetch + XOR swizzle + XCD-aware tile swizzle.
__global__ __launch_bounds__(512, 6)
void gemm_proj(const float* __restrict__ qin, const float* __restrict__ kin,
               const float* __restrict__ vin,
               const bf16* __restrict__ Wq_t, const bf16* __restrict__ Wk_t,
               const bf16* __restrict__ Wv_t,
               bf16* __restrict__ Yb, bf16* __restrict__ Kb, bf16* __restrict__ Vb)
{
    __shared__ __align__(16) bf16 As[2][64][64];
    __shared__ __align__(16) bf16 Bs[2][128][64];

    const int z = blockIdx.z;
    const float* A  = (z == 0) ? qin  : (z == 1) ? kin  : vin;
    const bf16*  Wt = (z == 0) ? Wq_t : (z == 1) ? Wk_t : Wv_t;
    bf16*        C  = (z == 0) ? Yb   : (z == 1) ? Kb   : Vb;

    // XCD-aware tile swizzle (256 % 8 == 0).
    const int bid  = blockIdx.x;                  // 0..255
    const int tile = (bid & 7) * 32 + (bid >> 3);
    const int m0 = (tile >> 1) * 64;
    const int n0 = (tile & 1) * 128;

    const int tid = threadIdx.x, lane = tid & 63, wave = tid >> 6;
    const int wr = wave >> 2, wc = wave & 3;   // wave: 32m x 32n
    const int q4 = lane >> 4, l16 = lane & 15;

    f32x4 acc[2][2] = {};
    const int ar = tid >> 3, ac8 = (tid & 7) * 8;    // A: 64r x 64 fp32
    const int br = tid >> 2, bc16 = (tid & 3) * 16;  // B: 128r x 64 bf16

    const float* aBase = &A[(long)(m0 + ar) * DM + ac8];
    const bf16*  bBase = &Wt[(long)(n0 + br) * DM + bc16];

    f32x4  pa0[2], pa1[2];
    bf16x8 pb0[2], pb1[2];
    #pragma unroll
    for (int p = 0; p < 2; ++p) {               // preload slabs 0,1
        const float* ap = aBase + p * 64;
        pa0[p] = *(const f32x4*)ap; pa1[p] = *(const f32x4*)(ap + 4);
        const bf16* bp = bBase + p * 64;
        pb0[p] = *(const bf16x8*)bp; pb1[p] = *(const bf16x8*)(bp + 8);
    }
    {   // stage slab 0 -> buf 0
        bf16x8 o;
        #pragma unroll
        for (int e = 0; e < 4; ++e) { o[e] = (bf16)pa0[0][e]; o[4 + e] = (bf16)pa1[0][e]; }
        *(bf16x8*)&As[0][ar][swz8(ar, ac8)]      = o;
        *(bf16x8*)&Bs[0][br][swz8(br, bc16)]     = pb0[0];
        *(bf16x8*)&Bs[0][br][swz8(br, bc16 + 8)] = pb1[0];
    }
    __syncthreads();

    #pragma unroll
    for (int s = 0; s < 16; ++s) {              // 16 slabs of BK=64
        const int cs = s & 1;                   // buffer/slot of slab s
        const int ns = cs ^ 1;                  // buffer/slot of slab s+1
        if (s + 2 < 16) {                       // refill slot cs with slab s+2
            const float* ap = aBase + (s + 2) * 64;
            pa0[cs] = *(const f32x4*)ap; pa1[cs] = *(const f32x4*)(ap + 4);
            const bf16* bp = bBase + (s + 2) * 64;
            pb0[cs] = *(const bf16x8*)bp; pb1[cs] = *(const bf16x8*)(bp + 8);
        }
        if (s + 1 < 16) {                       // stage slab s+1 -> other buffer
            bf16x8 o;
            #pragma unroll
            for (int e = 0; e < 4; ++e) { o[e] = (bf16)pa0[ns][e]; o[4 + e] = (bf16)pa1[ns][e]; }
            *(bf16x8*)&As[ns][ar][swz8(ar, ac8)]      = o;
            *(bf16x8*)&Bs[ns][br][swz8(br, bc16)]     = pb0[ns];
            *(bf16x8*)&Bs[ns][br][swz8(br, bc16 + 8)] = pb1[ns];
        }
        #pragma unroll
        for (int kk = 0; kk < 64; kk += 32) {
            const int ra = wr * 32 + l16, rb = wc * 32 + l16;
            bf16x8 a0 = *(const bf16x8*)&As[cs][ra     ][swz8(ra,      kk + q4 * 8)];
            bf16x8 a1 = *(const bf16x8*)&As[cs][ra + 16][swz8(ra + 16, kk + q4 * 8)];
            bf16x8 b0 = *(const bf16x8*)&Bs[cs][rb     ][swz8(rb,      kk + q4 * 8)];
            bf16x8 b1 = *(const bf16x8*)&Bs[cs][rb + 16][swz8(rb + 16, kk + q4 * 8)];
            acc[0][0] = __builtin_amdgcn_mfma_f32_16x16x32_bf16(a0, b0, acc[0][0], 0, 0, 0);
            acc[0][1] = __builtin_amdgcn_mfma_f32_16x16x32_bf16(a0, b1, acc[0][1], 0, 0, 0);
            acc[1][0] = __builtin_amdgcn_mfma_f32_16x16x32_bf16(a1, b0, acc[1][0], 0, 0, 0);
            acc[1][1] = __builtin_amdgcn_mfma_f32_16x16x32_bf16(a1, b1, acc[1][1], 0, 0, 0);
        }
        __syncthreads();
    }
    // C/D layout: col = lane&15, row = (lane>>4)*4 + reg. z==0 -> sigmoid.
    #pragma unroll
    for (int i = 0; i < 2; ++i)
        #pragma unroll
        for (int j = 0; j < 2; ++j)
            #pragma unroll
            for (int r = 0; r < 4; ++r) {
                int gm = m0 + wr * 32 + i * 16 + q4 * 4 + r;
                int gn = n0 + wc * 32 + j * 16 + l16;
                float v = acc[i][j][r];
                C[(long)gm * DH + gn] = (bf16)((z == 0) ? sigmoidf_(v) : v);
            }
}

// ---- exp-weighted reduction over j: ATOMIC-FREE partials -------------------
// 128 blocks x 256 thr, 16 j per block (2 rounds of 8; r4-verified loop).
// Final: per-block partial sums written to part[blk][2048] (coalesced) --
// replaces 524k global atomicAdds onto 2048 addresses (L2 serialization).
__global__ void reduce_kv(const bf16* __restrict__ Kb, const bf16* __restrict__ Vb,
                          float* __restrict__ part)
{
    __shared__ float red[2][4][B_][DH];     // [arr][wave][b][d] = 32 KB
    const int tid = threadIdx.x;
    const int g = tid & 31, jj = tid >> 5;  // 32 d-groups x 8 j
    const int d8 = g * 8;

    float sn[B_][8] = {}, sd[B_][8] = {};
    #pragma unroll
    for (int t2 = 0; t2 < 2; ++t2) {
        const int j = blockIdx.x * 16 + t2 * 8 + jj;
        bf16x8 kx[B_], vx[B_];
        #pragma unroll
        for (int b = 0; b < B_; ++b) {
            kx[b] = *(const bf16x8*)&Kb[((long)b * T_ + j) * DH + d8];
            vx[b] = *(const bf16x8*)&Vb[((long)b * T_ + j) * DH + d8];
        }
        #pragma unroll
        for (int e = 0; e < 8; ++e) {
            float k0 = (float)kx[0][e], k1 = (float)kx[1][e];
            float k2 = (float)kx[2][e], k3 = (float)kx[3][e];
            float mx = fmaxf(fmaxf(k0, k1), fmaxf(k2, k3));
            float e0 = __expf(k0 - mx), e1 = __expf(k1 - mx);
            float e2 = __expf(k2 - mx), e3 = __expf(k3 - mx);
            sn[0][e] += e0 * (float)vx[0][e]; sd[0][e] += e0;
            sn[1][e] += e1 * (float)vx[1][e]; sd[1][e] += e1;
            sn[2][e] += e2 * (float)vx[2][e]; sd[2][e] += e2;
            sn[3][e] += e3 * (float)vx[3][e]; sd[3][e] += e3;
        }
    }
    // combine jj with jj^1 (lanes l <-> l+32 within the wave)
    #pragma unroll
    for (int b = 0; b < B_; ++b)
        #pragma unroll
        for (int e = 0; e < 8; ++e) {
            sn[b][e] += __shfl_xor(sn[b][e], 32);
            sd[b][e] += __shfl_xor(sd[b][e], 32);
        }
    const int w = tid >> 6;
    if ((tid & 32) == 0) {                  // jj even holds the pair sum
        #pragma unroll
        for (int b = 0; b < B_; ++b)
            #pragma unroll
            for (int e = 0; e < 8; ++e) {
                red[0][w][b][d8 + e] = sn[b][e];
                red[1][w][b][d8 + e] = sd[b][e];
            }
    }
    __syncthreads();
    float* pout = &part[(long)blockIdx.x * 2048];
    #pragma unroll
    for (int o = tid; o < 2 * B_ * DH; o += 256) {
        const int arr = o >> 10, b = (o >> 8) & 3, d = o & 255;
        pout[o] = red[arr][0][b][d] + red[arr][1][b][d]
                + red[arr][2][b][d] + red[arr][3][b][d];
    }
}

// ---- merge partials -> rv = num/den ----------------------------------------
// 4 blocks x 256 thr; coalesced (lanes t..t+63 contiguous per blk slice);
// 1 MB reads, L2-hot.
__global__ void merge_kv(const float* __restrict__ part, float* __restrict__ rv)
{
    const int t = blockIdx.x * 256 + threadIdx.x;   // 0..1023 = b*DH + d
    float num = 0.f, den = 0.f;
    for (int blk = 0; blk < 128; ++blk) {
        num += part[(long)blk * 2048 + t];
        den += part[(long)blk * 2048 + 1024 + t];
    }
    rv[t] = num / den;
}

// ---- output GEMM: out = (Yb * rv[b]) @ Wo, fp32 out ------------------------
// ROUND-1 VERIFIED VERSION; only change: reads precomputed rv (no division).
__global__ __launch_bounds__(512, 6)
void gemm_out(const bf16* __restrict__ Yb, const bf16* __restrict__ Wo_t,
              const float* __restrict__ rv, float* __restrict__ out)
{
    __shared__ __align__(16) bf16 As[2][64][64];
    __shared__ __align__(16) bf16 Bs[2][128][64];
    __shared__ float rv_s[DH];

    // XCD-aware tile swizzle (1024 % 8 == 0): A panels (8x n-reuse) per XCD.
    const int bid  = blockIdx.x;                   // 0..1023
    const int tile = (bid & 7) * 128 + (bid >> 3);
    const int m0 = (tile >> 3) * 64;
    const int n0 = (tile & 7) * 128;
    const int b  = m0 >> 11;                       // batch = m0/2048

    const int tid = threadIdx.x, lane = tid & 63, wave = tid >> 6;
    const int wr = wave >> 2, wc = wave & 3;
    const int q4 = lane >> 4, l16 = lane & 15;

    if (tid < DH) rv_s[tid] = rv[b * DH + tid];

    f32x4 acc[2][2] = {};
    const int ar = tid >> 3, ac8 = (tid & 7) * 8;
    const int br = tid >> 2, bc16 = (tid & 3) * 16;

    const bf16* aBase = &Yb[(long)(m0 + ar) * DH + ac8];
    const bf16* bBase = &Wo_t[(long)(n0 + br) * DH + bc16];

    bf16x8 pq[2], pb0[2], pb1[2];
    #pragma unroll
    for (int p = 0; p < 2; ++p) {
        pq[p]  = *(const bf16x8*)(aBase + p * 64);
        const bf16* wp = bBase + p * 64;
        pb0[p] = *(const bf16x8*)wp; pb1[p] = *(const bf16x8*)(wp + 8);
    }
    __syncthreads();        // rv_s ready before staging uses it
    {   // stage slab 0 -> buf 0
        bf16x8 o;
        #pragma unroll
        for (int e = 0; e < 8; ++e)
            o[e] = (bf16)((float)pq[0][e] * rv_s[ac8 + e]);
        *(bf16x8*)&As[0][ar][swz8(ar, ac8)]      = o;
        *(bf16x8*)&Bs[0][br][swz8(br, bc16)]     = pb0[0];
        *(bf16x8*)&Bs[0][br][swz8(br, bc16 + 8)] = pb1[0];
    }
    __syncthreads();

    #pragma unroll
    for (int s = 0; s < 4; ++s) {               // 4 slabs of BK=64
        const int cs = s & 1, ns = cs ^ 1;
        if (s + 2 < 4) {
            pq[cs]  = *(const bf16x8*)(aBase + (s + 2) * 64);
            const bf16* wp = bBase + (s + 2) * 64;
            pb0[cs] = *(const bf16x8*)wp; pb1[cs] = *(const bf16x8*)(wp + 8);
        }
        if (s + 1 < 4) {
            bf16x8 o;
            #pragma unroll
            for (int e = 0; e < 8; ++e)
                o[e] = (bf16)((float)pq[ns][e] * rv_s[(s + 1) * 64 + ac8 + e]);
            *(bf16x8*)&As[ns][ar][swz8(ar, ac8)]      = o;
            *(bf16x8*)&Bs[ns][br][swz8(br, bc16)]     = pb0[ns];
            *(bf16x8*)&Bs[ns][br][swz8(br, bc16 + 8)] = pb1[ns];
        }
        #pragma unroll
        for (int kk = 0; kk < 64; kk += 32) {
            const int ra = wr * 32 + l16, rb = wc * 32 + l16;
            bf16x8 a0 = *(const bf16x8*)&As[cs][ra     ][swz8(ra,      kk + q4 * 8)];
            bf16x8 a1 = *(const bf16x8*)&As[cs][ra + 16][swz8(ra + 16, kk + q4 * 8)];
            bf16x8 b0 = *(const bf16x8*)&Bs[cs][rb     ][swz8(rb,      kk + q4 * 8)];
            bf16x8 b1 = *(const bf16x8*)&Bs[cs][rb + 16][swz8(rb + 16, kk + q4 * 8)];
            acc[0][0] = __builtin_amdgcn_mfma_f32_16x16x32_bf16(a0, b0, acc[0][0], 0, 0, 0);
            acc[0][1] = __builtin_amdgcn_mfma_f32_16x16x32_bf16(a0, b1, acc[0][1], 0, 0, 0);
            acc[1][0] = __builtin_amdgcn_mfma_f32_16x16x32_bf16(a1, b0, acc[1][0], 0, 0, 0);
            acc[1][1] = __builtin_amdgcn_mfma_f32_16x16x32_bf16(a1, b1, acc[1][1], 0, 0, 0);
        }
        __syncthreads();
    }
    #pragma unroll
    for (int i = 0; i < 2; ++i)
        #pragma unroll
        for (int j = 0; j < 2; ++j)
            #pragma unroll
            for (int r = 0; r < 4; ++r) {
                int gm = m0 + wr * 32 + i * 16 + q4 * 4 + r;
                int gn = n0 + wc * 32 + j * 16 + l16;
                out[(long)gm * DM + gn] = acc[i][j][r];
            }
}

// ---------------- launch ----------------
extern "C" void kernel_launch(void* const* d_in, const int* in_sizes, int n_in,
                              void* d_out, int out_size, void* d_ws, size_t ws_size,
                              hipStream_t stream)
{
    const float* q  = (const float*)d_in[0];
    const float* k  = (const float*)d_in[1];
    const float* v  = (const float*)d_in[2];
    const float* Wq = (const float*)d_in[3];
    const float* Wk = (const float*)d_in[4];
    const float* Wv = (const float*)d_in[5];
    const float* Wo = (const float*)d_in[6];
    // d_in[7] = W_bias: provably unused (exp_pos_bias == ones)
    float* out = (float*)d_out;

    // Workspace: 15.05 MB
    char* ws = (char*)d_ws;
    bf16* Yb    = (bf16*)ws;  ws += (size_t)M_ * DH * sizeof(bf16);   // sigmoid(Q), 4 MB
    bf16* Kb    = (bf16*)ws;  ws += (size_t)M_ * DH * sizeof(bf16);   // 4 MB
    bf16* Vb    = (bf16*)ws;  ws += (size_t)M_ * DH * sizeof(bf16);   // 4 MB
    bf16* Wq_t  = (bf16*)ws;  ws += (size_t)DM * DH * sizeof(bf16);   // 0.5 MB
    bf16* Wk_t  = (bf16*)ws;  ws += (size_t)DM * DH * sizeof(bf16);
    bf16* Wv_t  = (bf16*)ws;  ws += (size_t)DM * DH * sizeof(bf16);
    bf16* Wo_t  = (bf16*)ws;  ws += (size_t)DM * DH * sizeof(bf16);
    float* rv   = (float*)ws; ws += (size_t)B_ * DH * sizeof(float);  // 4 KB
    float* part = (float*)ws; ws += (size_t)128 * 2048 * sizeof(float); // 1 MB

    transpose_cvt_all<<<1024, 256, 0, stream>>>(Wq, Wk, Wv, Wo,
                                                Wq_t, Wk_t, Wv_t, Wo_t);

    gemm_proj<<<dim3(256, 1, 3), 512, 0, stream>>>(q, k, v, Wq_t, Wk_t, Wv_t,
                                                   Yb, Kb, Vb);
    reduce_kv<<<128, 256, 0, stream>>>(Kb, Vb, part);
    merge_kv<<<4, 256, 0, stream>>>(part, rv);
    gemm_out<<<1024, 512, 0, stream>>>(Yb, Wo_t, rv, out);
}

// Round 8
// 195.876 us; speedup vs baseline: 1.1304x; 1.0182x over previous
//
#include <hip/hip_runtime.h>
#include <hip/hip_bf16.h>
#include <math.h>

// Problem constants (all fp32 on the wire)
#define B_   4
#define T_   2048
#define DM   1024      // d_model
#define DH   256       // d_hidden
#define M_   (B_*T_)   // 8192 rows

typedef __bf16 bf16;
typedef __attribute__((ext_vector_type(8))) __bf16 bf16x8;
typedef __attribute__((ext_vector_type(4))) float  f32x4;

__device__ inline float sigmoidf_(float x) { return 1.0f / (1.0f + __expf(-x)); }

// T2-style LDS XOR swizzle: rows are 64 bf16 = 8 chunks of 16B.
// chunk' = chunk ^ (row & 7). Involution; same formula on write & read.
__device__ inline int swz8(int r, int c) { return (((c >> 3) ^ (r & 7)) << 3); }

// ---- transpose+convert 4 weights -------------------------------------------
__global__ void transpose_cvt_all(const float* __restrict__ Wq, const float* __restrict__ Wk,
                                  const float* __restrict__ Wv, const float* __restrict__ Wo,
                                  bf16* __restrict__ Wq_t, bf16* __restrict__ Wk_t,
                                  bf16* __restrict__ Wv_t, bf16* __restrict__ Wo_t)
{
    const int bid = blockIdx.x;
    __shared__ float tile[32][33];
    const int w = bid >> 8, t = bid & 255;
    const float* in; bf16* out; int R, C, sh;
    if      (w == 0) { in = Wq; out = Wq_t; R = DM; C = DH; sh = 3; }
    else if (w == 1) { in = Wk; out = Wk_t; R = DM; C = DH; sh = 3; }
    else if (w == 2) { in = Wv; out = Wv_t; R = DM; C = DH; sh = 3; }
    else             { in = Wo; out = Wo_t; R = DH; C = DM; sh = 5; }
    const int r0 = (t >> sh) * 32, c0 = (t & ((1 << sh) - 1)) * 32;
    const int tx = threadIdx.x & 31, ty = threadIdx.x >> 5;
    #pragma unroll
    for (int i = ty; i < 32; i += 8)
        tile[i][tx] = in[(long)(r0 + i) * C + c0 + tx];
    __syncthreads();
    #pragma unroll
    for (int i = ty; i < 32; i += 8)
        out[(long)(c0 + i) * R + r0 + tx] = (bf16)tile[tx][i];
}

// The r1-VERIFIED 64x128 BK=64 GEMM phase (dbuf, ring-2, swizzle). Invoked
// up to twice per block; all register indices static.
#define GEMM_PHASE(APTR, WT, ACC) {                                           \
    const float* aBase = &(APTR)[arowg * DM + ac8];                           \
    const bf16*  bBase = &(WT)[(long)(n0 + br) * DM + bc16];                  \
    f32x4 pa0[2], pa1[2]; bf16x8 pb0[2], pb1[2];                              \
    _Pragma("unroll")                                                         \
    for (int p = 0; p < 2; ++p) {                                             \
        const float* ap = aBase + p * 64;                                     \
        pa0[p] = *(const f32x4*)ap; pa1[p] = *(const f32x4*)(ap + 4);         \
        const bf16* bp = bBase + p * 64;                                      \
        pb0[p] = *(const bf16x8*)bp; pb1[p] = *(const bf16x8*)(bp + 8);       \
    }                                                                         \
    {   bf16x8 o;                                                             \
        _Pragma("unroll")                                                     \
        for (int e = 0; e < 4; ++e) { o[e] = (bf16)pa0[0][e]; o[4+e] = (bf16)pa1[0][e]; } \
        *(bf16x8*)&As[0][ar][swz8(ar, ac8)]      = o;                         \
        *(bf16x8*)&Bs[0][br][swz8(br, bc16)]     = pb0[0];                    \
        *(bf16x8*)&Bs[0][br][swz8(br, bc16 + 8)] = pb1[0];                    \
    }                                                                         \
    __syncthreads();                                                          \
    _Pragma("unroll")                                                         \
    for (int s = 0; s < 16; ++s) {                                            \
        const int cs = s & 1, ns = cs ^ 1;                                    \
        if (s + 2 < 16) {                                                     \
            const float* ap = aBase + (s + 2) * 64;                           \
            pa0[cs] = *(const f32x4*)ap; pa1[cs] = *(const f32x4*)(ap + 4);   \
            const bf16* bp = bBase + (s + 2) * 64;                            \
            pb0[cs] = *(const bf16x8*)bp; pb1[cs] = *(const bf16x8*)(bp + 8); \
        }                                                                     \
        if (s + 1 < 16) {                                                     \
            bf16x8 o;                                                         \
            _Pragma("unroll")                                                 \
            for (int e = 0; e < 4; ++e) { o[e] = (bf16)pa0[ns][e]; o[4+e] = (bf16)pa1[ns][e]; } \
            *(bf16x8*)&As[ns][ar][swz8(ar, ac8)]      = o;                    \
            *(bf16x8*)&Bs[ns][br][swz8(br, bc16)]     = pb0[ns];              \
            *(bf16x8*)&Bs[ns][br][swz8(br, bc16 + 8)] = pb1[ns];              \
        }                                                                     \
        _Pragma("unroll")                                                     \
        for (int kk = 0; kk < 64; kk += 32) {                                 \
            const int ra = wr * 32 + l16, rb = wc * 32 + l16;                 \
            bf16x8 a0 = *(const bf16x8*)&As[cs][ra     ][swz8(ra,      kk + q4 * 8)]; \
            bf16x8 a1 = *(const bf16x8*)&As[cs][ra + 16][swz8(ra + 16, kk + q4 * 8)]; \
            bf16x8 b0 = *(const bf16x8*)&Bs[cs][rb     ][swz8(rb,      kk + q4 * 8)]; \
            bf16x8 b1 = *(const bf16x8*)&Bs[cs][rb + 16][swz8(rb + 16, kk + q4 * 8)]; \
            ACC[0][0] = __builtin_amdgcn_mfma_f32_16x16x32_bf16(a0, b0, ACC[0][0], 0, 0, 0); \
            ACC[0][1] = __builtin_amdgcn_mfma_f32_16x16x32_bf16(a0, b1, ACC[0][1], 0, 0, 0); \
            ACC[1][0] = __builtin_amdgcn_mfma_f32_16x16x32_bf16(a1, b0, ACC[1][0], 0, 0, 0); \
            ACC[1][1] = __builtin_amdgcn_mfma_f32_16x16x32_bf16(a1, b1, ACC[1][1], 0, 0, 0); \
        }                                                                     \
        __syncthreads();                                                      \
    } }

// ---- fused projections + in-block KV reduction -----------------------------
// z==0 (256 blocks): Yb = sigmoid(q@Wq)   [r1-verified path]
// z==1 (256 blocks): rows = 4 batches x 16 j (row = b*16+jj). Computes K-tile
// and V-tile sequentially (two r1 GEMM phases), then reduces in-block:
// mx over b at each (j,d), e = exp(K-mx), partial num/den per (b,d) over 16 j.
// Kb/Vb global round-trip (16 MB) and the reduce_kv kernel are eliminated.
__global__ __launch_bounds__(512, 6)
void proj_fused(const float* __restrict__ qin, const float* __restrict__ kin,
                const float* __restrict__ vin,
                const bf16* __restrict__ Wq_t, const bf16* __restrict__ Wk_t,
                const bf16* __restrict__ Wv_t,
                bf16* __restrict__ Yb, float* __restrict__ part_num,
                float* __restrict__ part_den)
{
    __shared__ __align__(16) char smem[49152];
    auto As = reinterpret_cast<bf16 (*)[64][64]>(smem);            // [2][64][64], 16 KB
    auto Bs = reinterpret_cast<bf16 (*)[128][64]>(smem + 16384);   // [2][128][64], 32 KB

    const int z   = blockIdx.z;
    const int bid = blockIdx.x;                   // 0..255
    const int tile = (bid & 7) * 32 + (bid >> 3); // XCD-aware swizzle
    const int n0 = (tile & 1) * 128;

    const int tid = threadIdx.x, lane = tid & 63, wave = tid >> 6;
    const int wr = wave >> 2, wc = wave & 3;      // wave: 32m x 32n
    const int q4 = lane >> 4, l16 = lane & 15;
    const int ar = tid >> 3, ac8 = (tid & 7) * 8;    // A: 64r x 64 fp32
    const int br = tid >> 2, bc16 = (tid & 3) * 16;  // B: 128r x 64 bf16

    const int m0 = (tile >> 1) * 64;              // z==0: row tile
    const int jt = tile >> 1;                     // z==1: j tile (16 j's)
    // z==1 row map: tile row = b*16 + jj  ->  global row b*T + jt*16 + jj
    const long arowg = (z == 0) ? (long)(m0 + ar)
                                : (long)(ar >> 4) * T_ + jt * 16 + (ar & 15);

    f32x4 accA[2][2] = {};    // Q (z==0) or K (z==1)
    f32x4 accV[2][2] = {};    // V (z==1)

    if (z == 0) {
        GEMM_PHASE(qin, Wq_t, accA)
        // r1 epilogue: col = lane&15, row = (lane>>4)*4 + reg; sigmoid.
        #pragma unroll
        for (int i = 0; i < 2; ++i)
            #pragma unroll
            for (int j = 0; j < 2; ++j)
                #pragma unroll
                for (int r = 0; r < 4; ++r) {
                    int gm = m0 + wr * 32 + i * 16 + q4 * 4 + r;
                    int gn = n0 + wc * 32 + j * 16 + l16;
                    Yb[(long)gm * DH + gn] = (bf16)sigmoidf_(accA[i][j][r]);
                }
    } else {
        GEMM_PHASE(kin, Wk_t, accA)
        GEMM_PHASE(vin, Wv_t, accV)
        // Bounce K,V tiles to LDS as bf16 (same precision as old Kb/Vb path).
        auto KL = reinterpret_cast<bf16 (*)[128]>(smem);           // 16 KB
        auto VL = reinterpret_cast<bf16 (*)[128]>(smem + 16384);   // 16 KB
        float* red_n = (float*)(smem + 32768);                     // [4 grp][4 b][128], 8 KB
        float* red_d = (float*)(smem + 40960);                     // 8 KB
        #pragma unroll
        for (int i = 0; i < 2; ++i)
            #pragma unroll
            for (int j = 0; j < 2; ++j)
                #pragma unroll
                for (int r = 0; r < 4; ++r) {
                    const int row = wr * 32 + i * 16 + q4 * 4 + r;   // = b*16 + jj
                    const int col = wc * 32 + j * 16 + l16;
                    KL[row][col] = (bf16)accA[i][j][r];
                    VL[row][col] = (bf16)accV[i][j][r];
                }
        __syncthreads();
        // thread -> (d = tid&127, grp = tid>>7); grp covers 4 of the 16 j's.
        const int d = tid & 127, grp = tid >> 7;
        float sn0 = 0.f, sn1 = 0.f, sn2 = 0.f, sn3 = 0.f;
        float sd0 = 0.f, sd1 = 0.f, sd2 = 0.f, sd3 = 0.f;
        #pragma unroll
        for (int jj4 = 0; jj4 < 4; ++jj4) {
            const int jjj = grp * 4 + jj4;
            float k0 = (float)KL[jjj][d],      k1 = (float)KL[16 + jjj][d];
            float k2 = (float)KL[32 + jjj][d], k3 = (float)KL[48 + jjj][d];
            float mx = fmaxf(fmaxf(k0, k1), fmaxf(k2, k3));      // max over batch
            float e0 = __expf(k0 - mx), e1 = __expf(k1 - mx);
            float e2 = __expf(k2 - mx), e3 = __expf(k3 - mx);
            sn0 += e0 * (float)VL[jjj][d];      sd0 += e0;
            sn1 += e1 * (float)VL[16 + jjj][d]; sd1 += e1;
            sn2 += e2 * (float)VL[32 + jjj][d]; sd2 += e2;
            sn3 += e3 * (float)VL[48 + jjj][d]; sd3 += e3;
        }
        red_n[(grp * 4 + 0) * 128 + d] = sn0; red_d[(grp * 4 + 0) * 128 + d] = sd0;
        red_n[(grp * 4 + 1) * 128 + d] = sn1; red_d[(grp * 4 + 1) * 128 + d] = sd1;
        red_n[(grp * 4 + 2) * 128 + d] = sn2; red_d[(grp * 4 + 2) * 128 + d] = sd2;
        red_n[(grp * 4 + 3) * 128 + d] = sn3; red_d[(grp * 4 + 3) * 128 + d] = sd3;
        __syncthreads();
        {   // 512 threads = 4 b x 128 d: combine the 4 groups, write partials.
            const int b = tid >> 7, dd = tid & 127;
            float num = red_n[(b) * 128 + dd]      + red_n[(4 + b) * 128 + dd]
                      + red_n[(8 + b) * 128 + dd]  + red_n[(12 + b) * 128 + dd];
            float den = red_d[(b) * 128 + dd]      + red_d[(4 + b) * 128 + dd]
                      + red_d[(8 + b) * 128 + dd]  + red_d[(12 + b) * 128 + dd];
            const int idx = ((jt * 4 + b) << 8) + n0 + dd;
            part_num[idx] = num;
            part_den[idx] = den;
        }
    }
}

// ---- merge partials -> rv = num/den ----------------------------------------
// 4 blocks x 256 thr; t = b*256 + d; coalesced within each jt slice.
__global__ void merge_kv(const float* __restrict__ pn, const float* __restrict__ pd,
                         float* __restrict__ rv)
{
    const int t = blockIdx.x * 256 + threadIdx.x;   // 0..1023
    const int b = t >> 8, d = t & 255;
    float num = 0.f, den = 0.f;
    for (int jt = 0; jt < 128; ++jt) {
        num += pn[((jt * 4 + b) << 8) + d];
        den += pd[((jt * 4 + b) << 8) + d];
    }
    rv[t] = num / den;
}

// ---- output GEMM: out = (Yb * rv[b]) @ Wo, fp32 out ------------------------
// r7-VERIFIED VERSION (reads precomputed rv).
__global__ __launch_bounds__(512, 6)
void gemm_out(const bf16* __restrict__ Yb, const bf16* __restrict__ Wo_t,
              const float* __restrict__ rv, float* __restrict__ out)
{
    __shared__ __align__(16) bf16 As[2][64][64];
    __shared__ __align__(16) bf16 Bs[2][128][64];
    __shared__ float rv_s[DH];

    // XCD-aware tile swizzle (1024 % 8 == 0): A panels (8x n-reuse) per XCD.
    const int bid  = blockIdx.x;                   // 0..1023
    const int tile = (bid & 7) * 128 + (bid >> 3);
    const int m0 = (tile >> 3) * 64;
    const int n0 = (tile & 7) * 128;
    const int b  = m0 >> 11;                       // batch = m0/2048

    const int tid = threadIdx.x, lane = tid & 63, wave = tid >> 6;
    const int wr = wave >> 2, wc = wave & 3;
    const int q4 = lane >> 4, l16 = lane & 15;

    if (tid < DH) rv_s[tid] = rv[b * DH + tid];

    f32x4 acc[2][2] = {};
    const int ar = tid >> 3, ac8 = (tid & 7) * 8;
    const int br = tid >> 2, bc16 = (tid & 3) * 16;

    const bf16* aBase = &Yb[(long)(m0 + ar) * DH + ac8];
    const bf16* bBase = &Wo_t[(long)(n0 + br) * DH + bc16];

    bf16x8 pq[2], pb0[2], pb1[2];
    #pragma unroll
    for (int p = 0; p < 2; ++p) {
        pq[p]  = *(const bf16x8*)(aBase + p * 64);
        const bf16* wp = bBase + p * 64;
        pb0[p] = *(const bf16x8*)wp; pb1[p] = *(const bf16x8*)(wp + 8);
    }
    __syncthreads();        // rv_s ready before staging uses it
    {   // stage slab 0 -> buf 0
        bf16x8 o;
        #pragma unroll
        for (int e = 0; e < 8; ++e)
            o[e] = (bf16)((float)pq[0][e] * rv_s[ac8 + e]);
        *(bf16x8*)&As[0][ar][swz8(ar, ac8)]      = o;
        *(bf16x8*)&Bs[0][br][swz8(br, bc16)]     = pb0[0];
        *(bf16x8*)&Bs[0][br][swz8(br, bc16 + 8)] = pb1[0];
    }
    __syncthreads();

    #pragma unroll
    for (int s = 0; s < 4; ++s) {               // 4 slabs of BK=64
        const int cs = s & 1, ns = cs ^ 1;
        if (s + 2 < 4) {
            pq[cs]  = *(const bf16x8*)(aBase + (s + 2) * 64);
            const bf16* wp = bBase + (s + 2) * 64;
            pb0[cs] = *(const bf16x8*)wp; pb1[cs] = *(const bf16x8*)(wp + 8);
        }
        if (s + 1 < 4) {
            bf16x8 o;
            #pragma unroll
            for (int e = 0; e < 8; ++e)
                o[e] = (bf16)((float)pq[ns][e] * rv_s[(s + 1) * 64 + ac8 + e]);
            *(bf16x8*)&As[ns][ar][swz8(ar, ac8)]      = o;
            *(bf16x8*)&Bs[ns][br][swz8(br, bc16)]     = pb0[ns];
            *(bf16x8*)&Bs[ns][br][swz8(br, bc16 + 8)] = pb1[ns];
        }
        #pragma unroll
        for (int kk = 0; kk < 64; kk += 32) {
            const int ra = wr * 32 + l16, rb = wc * 32 + l16;
            bf16x8 a0 = *(const bf16x8*)&As[cs][ra     ][swz8(ra,      kk + q4 * 8)];
            bf16x8 a1 = *(const bf16x8*)&As[cs][ra + 16][swz8(ra + 16, kk + q4 * 8)];
            bf16x8 b0 = *(const bf16x8*)&Bs[cs][rb     ][swz8(rb,      kk + q4 * 8)];
            bf16x8 b1 = *(const bf16x8*)&Bs[cs][rb + 16][swz8(rb + 16, kk + q4 * 8)];
            acc[0][0] = __builtin_amdgcn_mfma_f32_16x16x32_bf16(a0, b0, acc[0][0], 0, 0, 0);
            acc[0][1] = __builtin_amdgcn_mfma_f32_16x16x32_bf16(a0, b1, acc[0][1], 0, 0, 0);
            acc[1][0] = __builtin_amdgcn_mfma_f32_16x16x32_bf16(a1, b0, acc[1][0], 0, 0, 0);
            acc[1][1] = __builtin_amdgcn_mfma_f32_16x16x32_bf16(a1, b1, acc[1][1], 0, 0, 0);
        }
        __syncthreads();
    }
    #pragma unroll
    for (int i = 0; i < 2; ++i)
        #pragma unroll
        for (int j = 0; j < 2; ++j)
            #pragma unroll
            for (int r = 0; r < 4; ++r) {
                int gm = m0 + wr * 32 + i * 16 + q4 * 4 + r;
                int gn = n0 + wc * 32 + j * 16 + l16;
                out[(long)gm * DM + gn] = acc[i][j][r];
            }
}

// ---------------- launch ----------------
extern "C" void kernel_launch(void* const* d_in, const int* in_sizes, int n_in,
                              void* d_out, int out_size, void* d_ws, size_t ws_size,
                              hipStream_t stream)
{
    const float* q  = (const float*)d_in[0];
    const float* k  = (const float*)d_in[1];
    const float* v  = (const float*)d_in[2];
    const float* Wq = (const float*)d_in[3];
    const float* Wk = (const float*)d_in[4];
    const float* Wv = (const float*)d_in[5];
    const float* Wo = (const float*)d_in[6];
    // d_in[7] = W_bias: provably unused (exp_pos_bias == ones)
    float* out = (float*)d_out;

    // Workspace: ~7.05 MB (Kb/Vb eliminated)
    char* ws = (char*)d_ws;
    bf16* Yb       = (bf16*)ws;  ws += (size_t)M_ * DH * sizeof(bf16);   // sigmoid(Q), 4 MB
    bf16* Wq_t     = (bf16*)ws;  ws += (size_t)DM * DH * sizeof(bf16);   // 0.5 MB
    bf16* Wk_t     = (bf16*)ws;  ws += (size_t)DM * DH * sizeof(bf16);
    bf16* Wv_t     = (bf16*)ws;  ws += (size_t)DM * DH * sizeof(bf16);
    bf16* Wo_t     = (bf16*)ws;  ws += (size_t)DM * DH * sizeof(bf16);
    float* rv      = (float*)ws; ws += (size_t)B_ * DH * sizeof(float);  // 4 KB
    float* part_n  = (float*)ws; ws += (size_t)128 * 4 * 256 * sizeof(float); // 512 KB
    float* part_d  = (float*)ws; ws += (size_t)128 * 4 * 256 * sizeof(float); // 512 KB

    transpose_cvt_all<<<1024, 256, 0, stream>>>(Wq, Wk, Wv, Wo,
                                                Wq_t, Wk_t, Wv_t, Wo_t);

    proj_fused<<<dim3(256, 1, 2), 512, 0, stream>>>(q, k, v, Wq_t, Wk_t, Wv_t,
                                                    Yb, part_n, part_d);
    merge_kv<<<4, 256, 0, stream>>>(part_n, part_d, rv);
    gemm_out<<<1024, 512, 0, stream>>>(Yb, Wo_t, rv, out);
}